// Round 1
// baseline (168.537 us; speedup 1.0000x reference)
//
#include <hip/hip_runtime.h>

// Problem shape is fixed by the reference: x (64,3,512,512) f32, mean_params (64,4) f32.
#define BB 64
#define CC 3
#define HH 512
#define WW 512
#define HW (HH * WW)           // 262144
#define CHW (CC * HH * WW)     // 786432

__global__ __launch_bounds__(256) void affine_sample_kernel(
    const float* __restrict__ x,
    const float* __restrict__ mp,
    float* __restrict__ out)
{
    int idx = blockIdx.x * blockDim.x + threadIdx.x;   // 0 .. B*H*W-1 (16.7M, fits int)
    int w = idx & (WW - 1);
    int h = (idx >> 9) & (HH - 1);
    int b = idx >> 18;
    int hw = idx & (HW - 1);     // h*W + w

    // per-batch affine params (broadcast loads, L1-resident: 64*16 B total)
    float theta = mp[b * 4 + 0];
    float scale = mp[b * 4 + 1];
    float tx    = mp[b * 4 + 2];
    float ty    = mp[b * 4 + 3];
    float s, c;
    sincosf(theta, &s, &c);
    float ct = scale * c;
    float st = scale * s;

    // normalized grid coords: xs=(2w+1)/W - 1, ys=(2h+1)/H - 1
    float xs = (2.0f * (float)w + 1.0f) * (1.0f / WW) - 1.0f;
    float ys = (2.0f * (float)h + 1.0f) * (1.0f / HH) - 1.0f;
    float gx = ct * xs - st * ys + tx;
    float gy = st * xs + ct * ys + ty;

    // unnormalize to input pixel space
    float ix = ((gx + 1.0f) * WW - 1.0f) * 0.5f;
    float iy = ((gy + 1.0f) * HH - 1.0f) * 0.5f;

    float x0f = floorf(ix);
    float y0f = floorf(iy);
    float fx = ix - x0f;
    float fy = iy - y0f;
    int x0 = (int)x0f;
    int y0 = (int)y0f;
    int x1 = x0 + 1;
    int y1 = y0 + 1;

    bool vx0 = (x0 >= 0) & (x0 < WW);
    bool vx1 = (x1 >= 0) & (x1 < WW);
    bool vy0 = (y0 >= 0) & (y0 < HH);
    bool vy1 = (y1 >= 0) & (y1 < HH);

    int x0c = min(max(x0, 0), WW - 1);
    int x1c = min(max(x1, 0), WW - 1);
    int y0c = min(max(y0, 0), HH - 1);
    int y1c = min(max(y1, 0), HH - 1);

    // bilinear weights, zeroed on invalid corners (matches reference's mask-multiply)
    float w00 = (1.0f - fx) * (1.0f - fy) * (float)(vy0 & vx0);
    float w01 = fx          * (1.0f - fy) * (float)(vy0 & vx1);
    float w10 = (1.0f - fx) * fy          * (float)(vy1 & vx0);
    float w11 = fx          * fy          * (float)(vy1 & vx1);

    int o00 = y0c * WW + x0c;
    int o01 = y0c * WW + x1c;
    int o10 = y1c * WW + x0c;
    int o11 = y1c * WW + x1c;

    const float* xb = x   + b * CHW;
    float*       ob = out + b * CHW;

#pragma unroll
    for (int ch = 0; ch < CC; ++ch) {
        const float* p = xb + ch * HW;
        float v = w00 * p[o00] + w01 * p[o01] + w10 * p[o10] + w11 * p[o11];
        ob[ch * HW + hw] = v;
    }
}

extern "C" void kernel_launch(void* const* d_in, const int* in_sizes, int n_in,
                              void* d_out, int out_size, void* d_ws, size_t ws_size,
                              hipStream_t stream)
{
    const float* x  = (const float*)d_in[0];
    const float* mp = (const float*)d_in[1];
    float* out = (float*)d_out;

    int total = BB * HH * WW;                // threads: one per (b,h,w)
    dim3 block(256);
    dim3 grid(total / 256);                  // 65536 blocks
    affine_sample_kernel<<<grid, block, 0, stream>>>(x, mp, out);
}

// Round 2
// 139.371 us; speedup vs baseline: 1.2093x; 1.2093x over previous
//
#include <hip/hip_runtime.h>

// x (64,3,512,512) f32, mean_params (64,4) f32.
#define BB 64
#define CC 3
#define HH 512
#define WW 512
#define HW (HH * WW)           // 262144
#define CHW (CC * HH * WW)     // 786432

// 2D tiling: wave = 8x8 output pixels, block (256 thr) = 16x16 tile (2x2 waves).
// Rationale: source coords rotate by (ct,st); a compact 8x8 output tile maps to a
// ~11x11 source patch (~13 cache lines/wave-load) vs a 64x1 strip's ~35 lines.
__global__ __launch_bounds__(256) void affine_sample_kernel(
    const float* __restrict__ x,
    const float* __restrict__ mp,
    float* __restrict__ out)
{
    int tid  = threadIdx.x;
    int lane = tid & 63;
    int wid  = tid >> 6;
    int lw = lane & 7;         // lane column within 8x8
    int lh = lane >> 3;        // lane row within 8x8
    int ww = wid & 1;          // wave column within 2x2
    int wh = wid >> 1;         // wave row within 2x2

    int bidx = blockIdx.x;     // 64 batches * 1024 tiles
    int b    = bidx >> 10;
    int rem  = bidx & 1023;    // 32x32 tiles of 16x16
    int tileH = (rem >> 5) << 4;
    int tileW = (rem & 31) << 4;

    int h = tileH + (wh << 3) + lh;
    int w = tileW + (ww << 3) + lw;

    // per-batch affine params (broadcast, L1-resident)
    float theta = mp[b * 4 + 0];
    float scale = mp[b * 4 + 1];
    float tx    = mp[b * 4 + 2];
    float ty    = mp[b * 4 + 3];
    float s, c;
    sincosf(theta, &s, &c);
    float ct = scale * c;
    float st = scale * s;

    float xs = (2.0f * (float)w + 1.0f) * (1.0f / WW) - 1.0f;
    float ys = (2.0f * (float)h + 1.0f) * (1.0f / HH) - 1.0f;
    float gx = ct * xs - st * ys + tx;
    float gy = st * xs + ct * ys + ty;

    float ix = ((gx + 1.0f) * WW - 1.0f) * 0.5f;
    float iy = ((gy + 1.0f) * HH - 1.0f) * 0.5f;

    float x0f = floorf(ix);
    float y0f = floorf(iy);
    float fx = ix - x0f;
    float fy = iy - y0f;
    int x0 = (int)x0f;
    int y0 = (int)y0f;
    int x1 = x0 + 1;
    int y1 = y0 + 1;

    bool vx0 = (x0 >= 0) & (x0 < WW);
    bool vx1 = (x1 >= 0) & (x1 < WW);
    bool vy0 = (y0 >= 0) & (y0 < HH);
    bool vy1 = (y1 >= 0) & (y1 < HH);

    int x0c = min(max(x0, 0), WW - 1);
    int x1c = min(max(x1, 0), WW - 1);
    int y0c = min(max(y0, 0), HH - 1);
    int y1c = min(max(y1, 0), HH - 1);

    float w00 = (1.0f - fx) * (1.0f - fy) * (float)(vy0 & vx0);
    float w01 = fx          * (1.0f - fy) * (float)(vy0 & vx1);
    float w10 = (1.0f - fx) * fy          * (float)(vy1 & vx0);
    float w11 = fx          * fy          * (float)(vy1 & vx1);

    int o00 = y0c * WW + x0c;
    int o01 = y0c * WW + x1c;
    int o10 = y1c * WW + x0c;
    int o11 = y1c * WW + x1c;

    const float* xb = x   + b * CHW;
    float*       ob = out + b * CHW + h * WW + w;

#pragma unroll
    for (int ch = 0; ch < CC; ++ch) {
        const float* p = xb + ch * HW;
        float v = w00 * p[o00] + w01 * p[o01] + w10 * p[o10] + w11 * p[o11];
        __builtin_nontemporal_store(v, ob + ch * HW);
    }
}

extern "C" void kernel_launch(void* const* d_in, const int* in_sizes, int n_in,
                              void* d_out, int out_size, void* d_ws, size_t ws_size,
                              hipStream_t stream)
{
    const float* x  = (const float*)d_in[0];
    const float* mp = (const float*)d_in[1];
    float* out = (float*)d_out;

    // 64 batches x (32x32) tiles of 16x16 px
    dim3 block(256);
    dim3 grid(BB * 1024);
    affine_sample_kernel<<<grid, block, 0, stream>>>(x, mp, out);
}

// Round 3
// 97.220 us; speedup vs baseline: 1.7336x; 1.4336x over previous
//
#include <hip/hip_runtime.h>

// x (64,3,512,512) f32, mean_params (64,4) f32.
#define BB 64
#define CC 3
#define HH 512
#define WW 512
#define HW (HH * WW)           // 262144
#define CHW (CC * HH * WW)     // 786432

// float2 with alignment 4: x-corner pair (x0,x1) is contiguous, fetched in ONE
// dwordx2 gather instead of two dword gathers (per-instruction cost dominates).
typedef float f2_t __attribute__((ext_vector_type(2), aligned(4)));

// Wave = 8x8 output pixels, block (256 thr) = 16x16 tile (2x2 waves).
__global__ __launch_bounds__(256) void affine_sample_kernel(
    const float* __restrict__ x,
    const float* __restrict__ mp,
    float* __restrict__ out)
{
    int tid  = threadIdx.x;
    int lane = tid & 63;
    int wid  = tid >> 6;
    int lw = lane & 7;
    int lh = lane >> 3;
    int ww = wid & 1;
    int wh = wid >> 1;

    int bidx = blockIdx.x;
    int b    = bidx >> 10;
    int rem  = bidx & 1023;
    int tileH = (rem >> 5) << 4;
    int tileW = (rem & 31) << 4;

    int h = tileH + (wh << 3) + lh;
    int w = tileW + (ww << 3) + lw;

    float theta = mp[b * 4 + 0];
    float scale = mp[b * 4 + 1];
    float tx    = mp[b * 4 + 2];
    float ty    = mp[b * 4 + 3];
    float s, c;
    sincosf(theta, &s, &c);
    float ct = scale * c;
    float st = scale * s;

    float xs = (2.0f * (float)w + 1.0f) * (1.0f / WW) - 1.0f;
    float ys = (2.0f * (float)h + 1.0f) * (1.0f / HH) - 1.0f;
    float gx = ct * xs - st * ys + tx;
    float gy = st * xs + ct * ys + ty;

    float ix = ((gx + 1.0f) * WW - 1.0f) * 0.5f;
    float iy = ((gy + 1.0f) * HH - 1.0f) * 0.5f;

    float x0f = floorf(ix);
    float y0f = floorf(iy);
    float fx = ix - x0f;
    float fy = iy - y0f;
    int x0 = (int)x0f;
    int y0 = (int)y0f;
    int y1 = y0 + 1;

    // x-side combined coefficients for the float2 (v.x, v.y) at base column
    float wl = 1.0f - fx;
    float wr = fx;
    bool interior = (x0 >= 0) & (x0 <= WW - 2);
    float al = interior ? wl : ((x0 == -1)     ? wr : 0.0f);
    float ar = interior ? wr : ((x0 == WW - 1) ? wl : 0.0f);
    int base = min(max(x0, 0), WW - 2);

    // y-side validity and weights
    bool vy0 = (y0 >= 0) & (y0 < HH);
    bool vy1 = (y1 >= 0) & (y1 < HH);
    int y0c = min(max(y0, 0), HH - 1);
    int y1c = min(max(y1, 0), HH - 1);
    float fy0 = (1.0f - fy) * (float)vy0;
    float fy1 = fy          * (float)vy1;

    float w00 = al * fy0;   // coeff of top v.x
    float w01 = ar * fy0;   // coeff of top v.y
    float w10 = al * fy1;   // coeff of bot v.x
    float w11 = ar * fy1;   // coeff of bot v.y

    int o0 = y0c * WW + base;
    int o1 = y1c * WW + base;

    const float* xb = x   + b * CHW;
    float*       ob = out + b * CHW + h * WW + w;

#pragma unroll
    for (int ch = 0; ch < CC; ++ch) {
        const float* p = xb + ch * HW;
        f2_t v0 = *(const f2_t*)(p + o0);
        f2_t v1 = *(const f2_t*)(p + o1);
        float v = w00 * v0.x + w01 * v0.y + w10 * v1.x + w11 * v1.y;
        __builtin_nontemporal_store(v, ob + ch * HW);
    }
}

extern "C" void kernel_launch(void* const* d_in, const int* in_sizes, int n_in,
                              void* d_out, int out_size, void* d_ws, size_t ws_size,
                              hipStream_t stream)
{
    const float* x  = (const float*)d_in[0];
    const float* mp = (const float*)d_in[1];
    float* out = (float*)d_out;

    dim3 block(256);
    dim3 grid(BB * 1024);
    affine_sample_kernel<<<grid, block, 0, stream>>>(x, mp, out);
}